// Round 9
// baseline (2365.359 us; speedup 1.0000x reference)
//
#include <hip/hip_runtime.h>
#include <math.h>

// Problem constants
// B=256, T=512, E=768, Hd=50, 4*Hd=200, H=100, K=11, START=9, STOP=10, NEG=-1000
// M = B*T = 131072

typedef _Float16 half8 __attribute__((ext_vector_type(8)));
typedef _Float16 half4 __attribute__((ext_vector_type(4)));
typedef float f32x4 __attribute__((ext_vector_type(4)));

// ---------------------------------------------------------------------------
// Kernel 1: xw[M][400] = emb[M][768] @ concat(W_ih_f, W_ih_b)^T
// Split-precision fp16 MFMA (hi+lo, 3 products) => ~fp32 accuracy at f16 rate.
// ---------------------------------------------------------------------------
__global__ __launch_bounds__(256) void k_gemm_split(
    const float* __restrict__ emb,
    const float* __restrict__ Wf,     // [200][768]
    const float* __restrict__ Wb,     // [200][768]
    float* __restrict__ xw)           // [M][400]
{
    __shared__ _Float16 Ah[128 * 64];
    __shared__ _Float16 Al[128 * 64];
    __shared__ _Float16 Bh[80 * 64];
    __shared__ _Float16 Bl[80 * 64];

    const int bid = blockIdx.x;
    const int wg  = (bid & 7) * 640 + (bid >> 3);
    const int mt  = wg / 5;
    const int nb  = wg - mt * 5;
    const size_t m0 = (size_t)mt * 128;
    const int n0 = nb * 80;

    const int tid  = threadIdx.x;
    const int lane = tid & 63;
    const int w    = tid >> 6;        // wave 0..3, rows w*32..+31
    const int grp  = lane >> 4;       // 0..3
    const int r16  = lane & 15;

    f32x4 acc[2][5];
    #pragma unroll
    for (int m = 0; m < 2; ++m)
        #pragma unroll
        for (int n = 0; n < 5; ++n) acc[m][n] = (f32x4){0.f, 0.f, 0.f, 0.f};

    for (int kt = 0; kt < 12; ++kt) {
        const int k0 = kt * 64;
        __syncthreads();

        #pragma unroll
        for (int j = 0; j < 8; ++j) {
            const int flat = j * 256 + tid;      // 0..2047 float4 slots
            const int row  = flat >> 4;          // 0..127
            const int q    = flat & 15;          // float4 col
            const float4 v = *(const float4*)(emb + (m0 + row) * 768 + k0 + q * 4);
            half4 hv, lv;
            hv[0] = (_Float16)v.x; lv[0] = (_Float16)(v.x - (float)hv[0]);
            hv[1] = (_Float16)v.y; lv[1] = (_Float16)(v.y - (float)hv[1]);
            hv[2] = (_Float16)v.z; lv[2] = (_Float16)(v.z - (float)hv[2]);
            hv[3] = (_Float16)v.w; lv[3] = (_Float16)(v.w - (float)hv[3]);
            const int s    = (q >> 1) ^ (row & 7);
            const int addr = row * 64 + s * 8 + (q & 1) * 4;
            *(half4*)(Ah + addr) = hv;
            *(half4*)(Al + addr) = lv;
        }
        #pragma unroll
        for (int j = 0; j < 5; ++j) {
            const int flat = j * 256 + tid;      // 0..1279
            const int row  = flat >> 4;          // 0..79
            const int q    = flat & 15;
            const int n    = n0 + row;
            const float* src = (n < 200) ? (Wf + (size_t)n * 768)
                                         : (Wb + (size_t)(n - 200) * 768);
            const float4 v = *(const float4*)(src + k0 + q * 4);
            half4 hv, lv;
            hv[0] = (_Float16)v.x; lv[0] = (_Float16)(v.x - (float)hv[0]);
            hv[1] = (_Float16)v.y; lv[1] = (_Float16)(v.y - (float)hv[1]);
            hv[2] = (_Float16)v.z; lv[2] = (_Float16)(v.z - (float)hv[2]);
            hv[3] = (_Float16)v.w; lv[3] = (_Float16)(v.w - (float)hv[3]);
            const int s    = (q >> 1) ^ (row & 7);
            const int addr = row * 64 + s * 8 + (q & 1) * 4;
            *(half4*)(Bh + addr) = hv;
            *(half4*)(Bl + addr) = lv;
        }
        __syncthreads();

        #pragma unroll
        for (int ks = 0; ks < 2; ++ks) {
            const int kslot = ks * 4 + grp;
            half8 ah[2], al[2], bh[5], bl[5];
            #pragma unroll
            for (int m = 0; m < 2; ++m) {
                const int row = w * 32 + m * 16 + r16;
                const int ad  = row * 64 + (kslot ^ (row & 7)) * 8;
                ah[m] = *(half8*)(Ah + ad);
                al[m] = *(half8*)(Al + ad);
            }
            #pragma unroll
            for (int n = 0; n < 5; ++n) {
                const int row = n * 16 + r16;
                const int ad  = row * 64 + (kslot ^ (row & 7)) * 8;
                bh[n] = *(half8*)(Bh + ad);
                bl[n] = *(half8*)(Bl + ad);
            }
            #pragma unroll
            for (int m = 0; m < 2; ++m)
                #pragma unroll
                for (int n = 0; n < 5; ++n) {
                    acc[m][n] = __builtin_amdgcn_mfma_f32_16x16x32_f16(ah[m], bh[n], acc[m][n], 0, 0, 0);
                    acc[m][n] = __builtin_amdgcn_mfma_f32_16x16x32_f16(ah[m], bl[n], acc[m][n], 0, 0, 0);
                    acc[m][n] = __builtin_amdgcn_mfma_f32_16x16x32_f16(al[m], bh[n], acc[m][n], 0, 0, 0);
                }
        }
    }

    #pragma unroll
    for (int m = 0; m < 2; ++m) {
        #pragma unroll
        for (int n = 0; n < 5; ++n) {
            #pragma unroll
            for (int i = 0; i < 4; ++i) {
                const size_t row = m0 + w * 32 + m * 16 + (lane >> 4) * 4 + i;
                const int    col = n0 + n * 16 + (lane & 15);
                xw[row * 400 + col] = acc[m][n][i];
            }
        }
    }
}

// ---------------------------------------------------------------------------
// Kernel 2: bidirectional LSTM recurrence — MFMA-BATCHED.
// 32 blocks = 16 batch-chunks x 2 dirs; each block advances 16 chains in
// lockstep. Per step: H[16x50] @ Whh^T[50x200] via split-fp16 MFMA (hi+lo,
// 3 products — same accuracy regime as k_gemm_split, which kept all Viterbi
// argmaxes exact), gate exchange through g_s, wave-parallel nonlinearity
// (<=4 (chain,unit) items per thread), h stored exact fp32 to hout and
// split hi/lo fp16 into the swizzled A-tile for the next step. X rows
// reg-staged one step ahead (drained by the mid __syncthreads), ds_written
// into a double buffer during the nonlin phase. End barrier is lgkmcnt-only
// so hout stores stay in flight.
// ---------------------------------------------------------------------------
__global__ __launch_bounds__(256, 1) void k_lstm(
    const float* __restrict__ xw,     // [131072][400] (fwd gates 0..199, bwd 200..399)
    const float* __restrict__ Whh_f,  // [200][50]
    const float* __restrict__ Whh_b,
    const float* __restrict__ bf_,    // [200]
    const float* __restrict__ bb_,
    float* __restrict__ hout)         // [131072][100] (fwd 0..49, bwd 50..99)
{
    const int dir = blockIdx.x >> 4;      // 0 fwd, 1 bwd
    const int bc  = blockIdx.x & 15;      // batch chunk: b = bc*16 + chain
    const int tid = threadIdx.x;
    const int wv  = tid >> 6;
    const int lane = tid & 63;
    const int grp  = lane >> 4;
    const int r16  = lane & 15;

    __shared__ _Float16 Bh[208 * 64];     // [gate][unit] hi, XOR-swizzled
    __shared__ _Float16 Bl[208 * 64];     // lo
    __shared__ _Float16 Ahh[16 * 64];     // h hi [chain][unit], swizzled
    __shared__ _Float16 Ahl[16 * 64];     // h lo
    __shared__ float g_s[16 * 208];       // hW exchange
    __shared__ float x_s[2][16 * 256];    // x double buffer (row pad 256)
    __shared__ float bias_s[208];

    const float* Whh  = dir ? Whh_b : Whh_f;
    const float* bias = dir ? bb_ : bf_;

    // Whh -> swizzled split B tiles (once)
    for (int i = tid; i < 208 * 64; i += 256) {
        const int gate = i >> 6, u = i & 63;
        const float w = (gate < 200 && u < 50) ? Whh[gate * 50 + u] : 0.f;
        const _Float16 hi = (_Float16)w;
        const _Float16 lo = (_Float16)(w - (float)hi);
        const int ad = gate * 64 + (((u >> 3) ^ (gate & 7)) * 8) + (u & 7);
        Bh[ad] = hi; Bl[ad] = lo;
    }
    for (int i = tid; i < 208; i += 256) bias_s[i] = (i < 200) ? bias[i] : 0.f;
    for (int i = tid; i < 16 * 64; i += 256) { Ahh[i] = (_Float16)0.f; Ahl[i] = (_Float16)0.f; }

    // per-thread (chain,unit) item map: 800 items over 256 threads
    int ch_[4], un_[4]; bool val_[4];
    #pragma unroll
    for (int j = 0; j < 4; ++j) {
        const int gi = tid + j * 256;
        val_[j] = (gi < 800);
        const int gic = val_[j] ? gi : 0;
        ch_[j] = gic / 50; un_[j] = gic % 50;
    }
    float cc[4] = {0.f, 0.f, 0.f, 0.f};

    const size_t bbase = (size_t)(bc * 16) * 512;

    // first x stage into x_s[0]
    {
        const int t0 = dir ? 511 : 0;
        #pragma unroll
        for (int j = 0; j < 4; ++j) if (val_[j]) {
            const float4 v = *(const float4*)(xw + (bbase + (size_t)ch_[j] * 512 + t0) * 400 + dir * 200 + un_[j] * 4);
            *(float4*)(&x_s[0][ch_[j] * 256 + un_[j] * 4]) = v;
        }
    }
    __syncthreads();

    // resident B fragments: wave wv owns n-tiles nt0..nt0+ncnt-1
    const int nt0  = (wv == 0) ? 0 : (wv == 1) ? 4 : (wv == 2) ? 7 : 10;
    const int ncnt = (wv == 0) ? 4 : 3;
    half8 bhf[4][2], blf[4][2];
    #pragma unroll
    for (int j = 0; j < 4; ++j)
        #pragma unroll
        for (int ks = 0; ks < 2; ++ks) {
            const int gate = (nt0 + ((j < ncnt) ? j : 0)) * 16 + r16;
            const int koct = ks * 4 + grp;
            const int ad = gate * 64 + ((koct ^ (gate & 7)) * 8);
            bhf[j][ks] = *(half8*)(Bh + ad);
            blf[j][ks] = *(half8*)(Bl + ad);
        }

    int cur = 0;
    for (int it = 0; it < 512; ++it) {
        const int t  = dir ? (511 - it) : it;
        const int tn = dir ? (510 - it) : (it + 1);

        // --- MFMA: hW = h_{t-1} @ Whh^T (split hi/lo, 3 products) ---
        f32x4 acc[4];
        #pragma unroll
        for (int j = 0; j < 4; ++j) acc[j] = (f32x4){0.f, 0.f, 0.f, 0.f};
        #pragma unroll
        for (int ks = 0; ks < 2; ++ks) {
            const int koct = ks * 4 + grp;
            const int aad = r16 * 64 + ((koct ^ (r16 & 7)) * 8);
            const half8 ah = *(half8*)(Ahh + aad);
            const half8 al = *(half8*)(Ahl + aad);
            #pragma unroll
            for (int j = 0; j < 4; ++j) if (j < ncnt) {
                acc[j] = __builtin_amdgcn_mfma_f32_16x16x32_f16(ah, bhf[j][ks], acc[j], 0, 0, 0);
                acc[j] = __builtin_amdgcn_mfma_f32_16x16x32_f16(ah, blf[j][ks], acc[j], 0, 0, 0);
                acc[j] = __builtin_amdgcn_mfma_f32_16x16x32_f16(al, bhf[j][ks], acc[j], 0, 0, 0);
            }
        }

        // --- issue next-step x loads into registers ---
        float4 xf[4];
        if (it + 1 < 512) {
            #pragma unroll
            for (int j = 0; j < 4; ++j) if (val_[j])
                xf[j] = *(const float4*)(xw + (bbase + (size_t)ch_[j] * 512 + tn) * 400 + dir * 200 + un_[j] * 4);
        }

        // --- acc -> g_s (C layout: col=lane&15, row=(lane>>4)*4+i) ---
        #pragma unroll
        for (int j = 0; j < 4; ++j) if (j < ncnt) {
            const int gate = (nt0 + j) * 16 + r16;
            #pragma unroll
            for (int i = 0; i < 4; ++i)
                g_s[(grp * 4 + i) * 208 + gate] = acc[j][i];
        }
        __syncthreads();   // g_s visible; x loads drained (vmcnt 0)

        // --- write next x into the other buffer ---
        if (it + 1 < 512) {
            #pragma unroll
            for (int j = 0; j < 4; ++j) if (val_[j])
                *(float4*)(&x_s[cur ^ 1][ch_[j] * 256 + un_[j] * 4]) = xf[j];
        }

        // --- nonlinearity + state update (wave-parallel, <=4 items/thread) ---
        #pragma unroll
        for (int j = 0; j < 4; ++j) if (val_[j]) {
            const int chain = ch_[j], u = un_[j];
            const float* gr = &g_s[chain * 208];
            const float* xr = &x_s[cur][chain * 256];
            const float gi_ = (xr[u]       + gr[u])       + bias_s[u];
            const float gf_ = (xr[50 + u]  + gr[50 + u])  + bias_s[50 + u];
            const float gg_ = (xr[100 + u] + gr[100 + u]) + bias_s[100 + u];
            const float go_ = (xr[150 + u] + gr[150 + u]) + bias_s[150 + u];
            const float si = __builtin_amdgcn_rcpf(1.f + __expf(-gi_));
            const float sf = __builtin_amdgcn_rcpf(1.f + __expf(-gf_));
            const float tg = 1.f - 2.f * __builtin_amdgcn_rcpf(__expf(2.f * gg_) + 1.f);
            cc[j] = sf * cc[j] + si * tg;
            const float th = 1.f - 2.f * __builtin_amdgcn_rcpf(__expf(2.f * cc[j]) + 1.f);
            const float so = __builtin_amdgcn_rcpf(1.f + __expf(-go_));
            const float h = so * th;
            hout[(bbase + (size_t)chain * 512 + t) * 100 + dir * 50 + u] = h;
            const _Float16 hhi = (_Float16)h;
            const _Float16 hlo = (_Float16)(h - (float)hhi);
            const int aad = chain * 64 + (((u >> 3) ^ (chain & 7)) * 8) + (u & 7);
            Ahh[aad] = hhi;
            Ahl[aad] = hlo;
        }
        // LDS-visibility-only barrier: hout stores stay in flight.
        asm volatile("s_waitcnt lgkmcnt(0)\n\ts_barrier" ::: "memory");
        cur ^= 1;
    }
}

// ---------------------------------------------------------------------------
// Kernel 3: emissions logits[bt][11] = hout[bt][100] @ Wout^T + bout
// ---------------------------------------------------------------------------
__global__ __launch_bounds__(256) void k_emis(
    const float* __restrict__ hout,   // [131072][100]
    const float* __restrict__ Wout,   // [11][100]
    const float* __restrict__ bout,   // [11]
    float* __restrict__ logits)       // [131072][11]
{
    __shared__ float Wl[1104];
    __shared__ float bl[11];
    const int tid = threadIdx.x;
    for (int i = tid; i < 1100; i += 256) Wl[i] = Wout[i];
    if (tid < 11) bl[tid] = bout[tid];
    __syncthreads();

    const size_t bt = (size_t)blockIdx.x * 256 + tid;
    const float4* h4 = (const float4*)(hout + bt * 100);
    float acc[11];
    #pragma unroll
    for (int k = 0; k < 11; ++k) acc[k] = bl[k];
    #pragma unroll
    for (int q = 0; q < 25; ++q) {
        float4 v = h4[q];
        #pragma unroll
        for (int k = 0; k < 11; ++k) {
            const float4 wv = *(const float4*)&Wl[k * 100 + q * 4];
            acc[k] = fmaf(v.x, wv.x, fmaf(v.y, wv.y, fmaf(v.z, wv.z, fmaf(v.w, wv.w, acc[k]))));
        }
    }
    #pragma unroll
    for (int k = 0; k < 11; ++k) logits[bt * 11 + k] = acc[k];
}

// ---------------------------------------------------------------------------
// Kernel 4: CRF forward scan + logsumexp score + fused Viterbi backtrace.
// Lane-parallel exp over the 121 (prev,cur) pairs; sequential per-column
// max/argmax and ordered sum on thread c -> bitwise-identical outputs.
// ---------------------------------------------------------------------------
__global__ __launch_bounds__(64, 1) void k_crf(
    const float* __restrict__ logits,   // [131072][11]
    const int* __restrict__ mask,       // [256][512]
    const float* __restrict__ trans,    // [11][11]
    float* __restrict__ scores,         // [256]
    float* __restrict__ paths)          // [256][512] (as float)
{
    const int b = blockIdx.x;
    const int lane = threadIdx.x;

    __shared__ float smat[11 * 12];     // [c][p], pad 12
    __shared__ float emat[11 * 12];
    __shared__ unsigned char bp[512][12];

    const int  pA = lane / 11, cA = lane - pA * 11;
    const bool hasB = (lane < 57);
    const int  iB = hasB ? (lane + 64) : 0;
    const int  pB = iB / 11, cB = iB - pB * 11;

    const float trA = trans[pA * 11 + cA];
    const float trB = hasB ? trans[pB * 11 + cB] : 0.f;

    float al_c = (lane == 9) ? 0.f : -1000.f;   // alpha[c] lives in lane c (<11)

    const size_t lbase = (size_t)b * 512;

    float fA = logits[lbase * 11 + cA];
    float fB = hasB ? logits[lbase * 11 + cB] : 0.f;
    int   m_cur = mask[lbase];

    for (int t = 0; t < 512; ++t) {
        float fA_n = 0.f, fB_n = 0.f; int m_n = 1;
        if (t + 1 < 512) {
            fA_n = logits[(lbase + t + 1) * 11 + cA];
            if (hasB) fB_n = logits[(lbase + t + 1) * 11 + cB];
            m_n = mask[lbase + t + 1];
        }

        const float alA = __shfl(al_c, pA);
        const float alB = __shfl(al_c, pB);
        const float vvA = (alA + fA) + trA;
        const float vvB = (alB + fB) + trB;
        smat[cA * 12 + pA] = vvA;
        if (hasB) smat[cB * 12 + pB] = vvB;

        float vmax = -1e30f; int amax = 0;
        if (lane < 11) {
            float v[11];
            #pragma unroll
            for (int p = 0; p < 11; ++p) v[p] = smat[lane * 12 + p];
            #pragma unroll
            for (int p = 0; p < 11; ++p) {
                if (v[p] > vmax) { vmax = v[p]; amax = p; }
            }
        }
        const float vmA = __shfl(vmax, cA);
        const float vmB = __shfl(vmax, cB);

        const float eA = expf(vvA - vmA);
        const float eB = expf(vvB - vmB);
        emat[cA * 12 + pA] = eA;
        if (hasB) emat[cB * 12 + pB] = eB;

        if (lane < 11) {
            float e[11];
            #pragma unroll
            for (int p = 0; p < 11; ++p) e[p] = emat[lane * 12 + p];
            float s = 0.f;
            #pragma unroll
            for (int p = 0; p < 11; ++p) s += e[p];   // ordered p=0..10
            const float na = vmax + logf(s);
            if (m_cur > 0) {
                al_c = na;
                bp[t][lane] = (unsigned char)amax;
            } else {
                bp[t][lane] = (unsigned char)lane;
            }
        }
        fA = fA_n; fB = fB_n; m_cur = m_n;
    }

    // final scores + argmax (STOP = 10)
    float fin = (lane < 11) ? (al_c + trans[lane * 11 + 10]) : -1e30f;
    float m = fin;
    int am = (lane < 11) ? lane : 1000;
    #pragma unroll
    for (int off = 8; off >= 1; off >>= 1) {
        float om = __shfl_xor(m, off, 16);
        int   oa = __shfl_xor(am, off, 16);
        if (om > m || (om == m && oa < am)) { m = om; am = oa; }
    }
    float s = (lane < 11) ? expf(fin - m) : 0.f;
    #pragma unroll
    for (int off = 8; off >= 1; off >>= 1) s += __shfl_xor(s, off, 16);

    if (lane == 0) {
        scores[b] = m + logf(s);
        int cur = am;
        paths[lbase + 511] = (float)cur;
        for (int t = 511; t >= 1; --t) {
            cur = bp[t][cur];
            paths[lbase + t - 1] = (float)cur;
        }
    }
}

// ---------------------------------------------------------------------------
extern "C" void kernel_launch(void* const* d_in, const int* in_sizes, int n_in,
                              void* d_out, int out_size, void* d_ws, size_t ws_size,
                              hipStream_t stream) {
    const float* emb   = (const float*)d_in[0];
    const int*   imask = (const int*)d_in[1];
    const float* Wihf  = (const float*)d_in[2];
    const float* Whhf  = (const float*)d_in[3];
    const float* bf_   = (const float*)d_in[4];
    const float* Wihb  = (const float*)d_in[5];
    const float* Whhb  = (const float*)d_in[6];
    const float* bb_   = (const float*)d_in[7];
    const float* Wout  = (const float*)d_in[8];
    const float* bout  = (const float*)d_in[9];
    const float* trans = (const float*)d_in[10];

    float* out = (float*)d_out;
    float* ws  = (float*)d_ws;
    float* xw     = ws;                          // 131072*400 f32 = 209.7 MB
    float* hout   = xw + (size_t)131072 * 400;   // 131072*100 f32 = 52.4 MB
    float* logits = hout + (size_t)131072 * 100; // 131072*11  f32 = 5.8 MB

    k_gemm_split<<<5120, 256, 0, stream>>>(emb, Wihf, Wihb, xw);
    k_lstm<<<32, 256, 0, stream>>>(xw, Whhf, Whhb, bf_, bb_, hout);
    k_emis<<<512, 256, 0, stream>>>(hout, Wout, bout, logits);
    k_crf<<<256, 64, 0, stream>>>(logits, imask, trans, out, out + 256);
}

// Round 10
// 1223.163 us; speedup vs baseline: 1.9338x; 1.9338x over previous
//
#include <hip/hip_runtime.h>
#include <math.h>

// Problem constants
// B=256, T=512, E=768, Hd=50, 4*Hd=200, H=100, K=11, START=9, STOP=10, NEG=-1000
// M = B*T = 131072

typedef _Float16 half8 __attribute__((ext_vector_type(8)));
typedef _Float16 half4 __attribute__((ext_vector_type(4)));
typedef float f32x4 __attribute__((ext_vector_type(4)));

// Non-draining workgroup barrier: LDS-visibility only. No "memory" clobber
// (a clobber forces conservative vmem ordering/drain — the R3/R7 mistake);
// sched_barrier(0) pins ds ops on both sides (learn_hip m201 pattern).
#define LBAR() do {                                   \
    __builtin_amdgcn_sched_barrier(0);                \
    asm volatile("s_waitcnt lgkmcnt(0)");             \
    __builtin_amdgcn_s_barrier();                     \
    __builtin_amdgcn_sched_barrier(0);                \
} while (0)

// ---------------------------------------------------------------------------
// Kernel 1: xw[M][400] = emb[M][768] @ concat(W_ih_f, W_ih_b)^T
// Split-precision fp16 MFMA (hi+lo, 3 products) => ~fp32 accuracy at f16 rate.
// ---------------------------------------------------------------------------
__global__ __launch_bounds__(256) void k_gemm_split(
    const float* __restrict__ emb,
    const float* __restrict__ Wf,     // [200][768]
    const float* __restrict__ Wb,     // [200][768]
    float* __restrict__ xw)           // [M][400]
{
    __shared__ _Float16 Ah[128 * 64];
    __shared__ _Float16 Al[128 * 64];
    __shared__ _Float16 Bh[80 * 64];
    __shared__ _Float16 Bl[80 * 64];

    const int bid = blockIdx.x;
    const int wg  = (bid & 7) * 640 + (bid >> 3);
    const int mt  = wg / 5;
    const int nb  = wg - mt * 5;
    const size_t m0 = (size_t)mt * 128;
    const int n0 = nb * 80;

    const int tid  = threadIdx.x;
    const int lane = tid & 63;
    const int w    = tid >> 6;        // wave 0..3, rows w*32..+31
    const int grp  = lane >> 4;       // 0..3
    const int r16  = lane & 15;

    f32x4 acc[2][5];
    #pragma unroll
    for (int m = 0; m < 2; ++m)
        #pragma unroll
        for (int n = 0; n < 5; ++n) acc[m][n] = (f32x4){0.f, 0.f, 0.f, 0.f};

    for (int kt = 0; kt < 12; ++kt) {
        const int k0 = kt * 64;
        __syncthreads();

        #pragma unroll
        for (int j = 0; j < 8; ++j) {
            const int flat = j * 256 + tid;      // 0..2047 float4 slots
            const int row  = flat >> 4;          // 0..127
            const int q    = flat & 15;          // float4 col
            const float4 v = *(const float4*)(emb + (m0 + row) * 768 + k0 + q * 4);
            half4 hv, lv;
            hv[0] = (_Float16)v.x; lv[0] = (_Float16)(v.x - (float)hv[0]);
            hv[1] = (_Float16)v.y; lv[1] = (_Float16)(v.y - (float)hv[1]);
            hv[2] = (_Float16)v.z; lv[2] = (_Float16)(v.z - (float)hv[2]);
            hv[3] = (_Float16)v.w; lv[3] = (_Float16)(v.w - (float)hv[3]);
            const int s    = (q >> 1) ^ (row & 7);
            const int addr = row * 64 + s * 8 + (q & 1) * 4;
            *(half4*)(Ah + addr) = hv;
            *(half4*)(Al + addr) = lv;
        }
        #pragma unroll
        for (int j = 0; j < 5; ++j) {
            const int flat = j * 256 + tid;      // 0..1279
            const int row  = flat >> 4;          // 0..79
            const int q    = flat & 15;
            const int n    = n0 + row;
            const float* src = (n < 200) ? (Wf + (size_t)n * 768)
                                         : (Wb + (size_t)(n - 200) * 768);
            const float4 v = *(const float4*)(src + k0 + q * 4);
            half4 hv, lv;
            hv[0] = (_Float16)v.x; lv[0] = (_Float16)(v.x - (float)hv[0]);
            hv[1] = (_Float16)v.y; lv[1] = (_Float16)(v.y - (float)hv[1]);
            hv[2] = (_Float16)v.z; lv[2] = (_Float16)(v.z - (float)hv[2]);
            hv[3] = (_Float16)v.w; lv[3] = (_Float16)(v.w - (float)hv[3]);
            const int s    = (q >> 1) ^ (row & 7);
            const int addr = row * 64 + s * 8 + (q & 1) * 4;
            *(half4*)(Bh + addr) = hv;
            *(half4*)(Bl + addr) = lv;
        }
        __syncthreads();

        #pragma unroll
        for (int ks = 0; ks < 2; ++ks) {
            const int kslot = ks * 4 + grp;
            half8 ah[2], al[2], bh[5], bl[5];
            #pragma unroll
            for (int m = 0; m < 2; ++m) {
                const int row = w * 32 + m * 16 + r16;
                const int ad  = row * 64 + (kslot ^ (row & 7)) * 8;
                ah[m] = *(half8*)(Ah + ad);
                al[m] = *(half8*)(Al + ad);
            }
            #pragma unroll
            for (int n = 0; n < 5; ++n) {
                const int row = n * 16 + r16;
                const int ad  = row * 64 + (kslot ^ (row & 7)) * 8;
                bh[n] = *(half8*)(Bh + ad);
                bl[n] = *(half8*)(Bl + ad);
            }
            #pragma unroll
            for (int m = 0; m < 2; ++m)
                #pragma unroll
                for (int n = 0; n < 5; ++n) {
                    acc[m][n] = __builtin_amdgcn_mfma_f32_16x16x32_f16(ah[m], bh[n], acc[m][n], 0, 0, 0);
                    acc[m][n] = __builtin_amdgcn_mfma_f32_16x16x32_f16(ah[m], bl[n], acc[m][n], 0, 0, 0);
                    acc[m][n] = __builtin_amdgcn_mfma_f32_16x16x32_f16(al[m], bh[n], acc[m][n], 0, 0, 0);
                }
        }
    }

    #pragma unroll
    for (int m = 0; m < 2; ++m) {
        #pragma unroll
        for (int n = 0; n < 5; ++n) {
            #pragma unroll
            for (int i = 0; i < 4; ++i) {
                const size_t row = m0 + w * 32 + m * 16 + (lane >> 4) * 4 + i;
                const int    col = n0 + n * 16 + (lane & 15);
                xw[row * 400 + col] = acc[m][n][i];
            }
        }
    }
}

// ---------------------------------------------------------------------------
// Kernel 2: bidirectional LSTM recurrence. One block per (batch, dir) —
// R1's 512-block shape (best measured) with the three per-step taxes fixed:
//  (a) weights in LDS (WT4, transposed+vectorized: thread g reads its 4
//      weights per q as one conflict-free ds_read_b128) — kills the
//      ~200B/thread/step L2 re-fetch the register allocator forced;
//  (b) non-draining barriers (LBAR: lgkmcnt-only, NO memory clobber) +
//      8-deep x prefetch ring + 8-step hout store bursts — global ops
//      stay in flight across steps;
//  (c) fast transcendentals in the nonlinearity (R2 forms, absmax-0 proven).
// ---------------------------------------------------------------------------
__global__ __launch_bounds__(256) void k_lstm(
    const float* __restrict__ xw,     // [131072][400] (fwd gates 0..199, bwd 200..399)
    const float* __restrict__ Whh_f,  // [200][50]
    const float* __restrict__ Whh_b,
    const float* __restrict__ bf_,    // [200]
    const float* __restrict__ bb_,
    float* __restrict__ hout)         // [131072][100] (fwd 0..49, bwd 50..99)
{
    const int b   = blockIdx.x >> 1;
    const int dir = blockIdx.x & 1;
    const int g   = threadIdx.x;

    __shared__ __align__(16) float WT4[13][256][4];   // 53248 B weights
    __shared__ __align__(16) float hb[2][52];
    __shared__ float g_s[200];

    const float* Whh  = dir ? Whh_b : Whh_f;
    const float* bias = dir ? bb_ : bf_;

    // zero-fill, then transposed fill: WT4[k>>2][row][k&3] = Whh[row][k]
    for (int i = g; i < 13 * 256 * 4; i += 256) ((float*)WT4)[i] = 0.f;
    __syncthreads();
    for (int s = g; s < 10000; s += 256) {
        const int row = s / 50;
        const int k   = s - row * 50;
        WT4[k >> 2][row][k & 3] = Whh[s];
    }
    const bool gl200 = (g < 200);
    const bool gl50  = (g < 50);
    const float bg = gl200 ? bias[g] : 0.f;
    if (g < 104) ((float*)hb)[g] = 0.f;
    float c = 0.f;
    __syncthreads();

    const size_t base = (size_t)b * 512;
    const int col = dir * 200 + (gl200 ? g : 0);
    const float* wbase = &WT4[0][gl200 ? g : 0][0];   // q-stride 1024 floats

    float xv[8];
    #pragma unroll
    for (int k = 0; k < 8; ++k) {
        const int tt = dir ? (511 - k) : k;
        xv[k] = gl200 ? xw[(base + tt) * 400 + col] : 0.f;
    }
    float hreg[8];

    int cur = 0;
    for (int it0 = 0; it0 < 512; it0 += 8) {
        #pragma unroll
        for (int k = 0; k < 8; ++k) {
            const int it = it0 + k;
            const float xcur = xv[k];
            if (it + 8 < 512) {
                const int tn = dir ? (511 - (it + 8)) : (it + 8);
                if (gl200) xv[k] = xw[(base + tn) * 400 + col];
            }

            // dot: gate pre-activation (order identical to R2's passing form)
            const f32x4* h4 = (const f32x4*)(&hb[cur][0]);
            float s0 = bg + xcur, s1 = 0.f, s2 = 0.f, s3 = 0.f;
            #pragma unroll
            for (int q = 0; q < 13; ++q) {
                const f32x4 wq = *(const f32x4*)(wbase + q * 1024);
                const f32x4 hv = h4[q];
                s0 = fmaf(wq[0], hv[0], s0);
                s1 = fmaf(wq[1], hv[1], s1);
                s2 = fmaf(wq[2], hv[2], s2);
                s3 = fmaf(wq[3], hv[3], s3);
            }
            const float sum = (s0 + s1) + (s2 + s3);
            if (gl200) g_s[g] = sum;
            LBAR();

            if (gl50) {
                const float gi = g_s[g];
                const float gf = g_s[g + 50];
                const float gg = g_s[g + 100];
                const float go = g_s[g + 150];
                const float si = __builtin_amdgcn_rcpf(1.f + __expf(-gi));
                const float sf = __builtin_amdgcn_rcpf(1.f + __expf(-gf));
                const float tg = 1.f - 2.f * __builtin_amdgcn_rcpf(__expf(2.f * gg) + 1.f);
                c = sf * c + si * tg;
                const float th = 1.f - 2.f * __builtin_amdgcn_rcpf(__expf(2.f * c) + 1.f);
                const float so = __builtin_amdgcn_rcpf(1.f + __expf(-go));
                const float h = so * th;
                hreg[k] = h;
                hb[cur ^ 1][g] = h;
            }
            LBAR();
            cur ^= 1;
        }
        // burst-store 8 h values (fire-and-forget; no barrier drains them)
        if (gl50) {
            #pragma unroll
            for (int r = 0; r < 8; ++r) {
                const int tr_ = dir ? (511 - (it0 + r)) : (it0 + r);
                hout[(base + tr_) * 100 + dir * 50 + g] = hreg[r];
            }
        }
    }
}

// ---------------------------------------------------------------------------
// Kernel 3: emissions logits[bt][11] = hout[bt][100] @ Wout^T + bout
// ---------------------------------------------------------------------------
__global__ __launch_bounds__(256) void k_emis(
    const float* __restrict__ hout,   // [131072][100]
    const float* __restrict__ Wout,   // [11][100]
    const float* __restrict__ bout,   // [11]
    float* __restrict__ logits)       // [131072][11]
{
    __shared__ float Wl[1104];
    __shared__ float bl[11];
    const int tid = threadIdx.x;
    for (int i = tid; i < 1100; i += 256) Wl[i] = Wout[i];
    if (tid < 11) bl[tid] = bout[tid];
    __syncthreads();

    const size_t bt = (size_t)blockIdx.x * 256 + tid;
    const float4* h4 = (const float4*)(hout + bt * 100);
    float acc[11];
    #pragma unroll
    for (int k = 0; k < 11; ++k) acc[k] = bl[k];
    #pragma unroll
    for (int q = 0; q < 25; ++q) {
        float4 v = h4[q];
        #pragma unroll
        for (int k = 0; k < 11; ++k) {
            const float4 wv = *(const float4*)&Wl[k * 100 + q * 4];
            acc[k] = fmaf(v.x, wv.x, fmaf(v.y, wv.y, fmaf(v.z, wv.z, fmaf(v.w, wv.w, acc[k]))));
        }
    }
    #pragma unroll
    for (int k = 0; k < 11; ++k) logits[bt * 11 + k] = acc[k];
}

// ---------------------------------------------------------------------------
// Kernel 4: CRF forward scan + logsumexp score + fused Viterbi backtrace.
// Lane-parallel exp over the 121 (prev,cur) pairs; sequential per-column
// max/argmax and ordered sum on thread c -> bitwise-identical outputs.
// ---------------------------------------------------------------------------
__global__ __launch_bounds__(64, 1) void k_crf(
    const float* __restrict__ logits,   // [131072][11]
    const int* __restrict__ mask,       // [256][512]
    const float* __restrict__ trans,    // [11][11]
    float* __restrict__ scores,         // [256]
    float* __restrict__ paths)          // [256][512] (as float)
{
    const int b = blockIdx.x;
    const int lane = threadIdx.x;

    __shared__ float smat[11 * 12];     // [c][p], pad 12
    __shared__ float emat[11 * 12];
    __shared__ unsigned char bp[512][12];

    const int  pA = lane / 11, cA = lane - pA * 11;
    const bool hasB = (lane < 57);
    const int  iB = hasB ? (lane + 64) : 0;
    const int  pB = iB / 11, cB = iB - pB * 11;

    const float trA = trans[pA * 11 + cA];
    const float trB = hasB ? trans[pB * 11 + cB] : 0.f;

    float al_c = (lane == 9) ? 0.f : -1000.f;   // alpha[c] lives in lane c (<11)

    const size_t lbase = (size_t)b * 512;

    float fA = logits[lbase * 11 + cA];
    float fB = hasB ? logits[lbase * 11 + cB] : 0.f;
    int   m_cur = mask[lbase];

    for (int t = 0; t < 512; ++t) {
        float fA_n = 0.f, fB_n = 0.f; int m_n = 1;
        if (t + 1 < 512) {
            fA_n = logits[(lbase + t + 1) * 11 + cA];
            if (hasB) fB_n = logits[(lbase + t + 1) * 11 + cB];
            m_n = mask[lbase + t + 1];
        }

        const float alA = __shfl(al_c, pA);
        const float alB = __shfl(al_c, pB);
        const float vvA = (alA + fA) + trA;
        const float vvB = (alB + fB) + trB;
        smat[cA * 12 + pA] = vvA;
        if (hasB) smat[cB * 12 + pB] = vvB;

        float vmax = -1e30f; int amax = 0;
        if (lane < 11) {
            float v[11];
            #pragma unroll
            for (int p = 0; p < 11; ++p) v[p] = smat[lane * 12 + p];
            #pragma unroll
            for (int p = 0; p < 11; ++p) {
                if (v[p] > vmax) { vmax = v[p]; amax = p; }
            }
        }
        const float vmA = __shfl(vmax, cA);
        const float vmB = __shfl(vmax, cB);

        const float eA = expf(vvA - vmA);
        const float eB = expf(vvB - vmB);
        emat[cA * 12 + pA] = eA;
        if (hasB) emat[cB * 12 + pB] = eB;

        if (lane < 11) {
            float e[11];
            #pragma unroll
            for (int p = 0; p < 11; ++p) e[p] = emat[lane * 12 + p];
            float s = 0.f;
            #pragma unroll
            for (int p = 0; p < 11; ++p) s += e[p];   // ordered p=0..10
            const float na = vmax + logf(s);
            if (m_cur > 0) {
                al_c = na;
                bp[t][lane] = (unsigned char)amax;
            } else {
                bp[t][lane] = (unsigned char)lane;
            }
        }
        fA = fA_n; fB = fB_n; m_cur = m_n;
    }

    // final scores + argmax (STOP = 10)
    float fin = (lane < 11) ? (al_c + trans[lane * 11 + 10]) : -1e30f;
    float m = fin;
    int am = (lane < 11) ? lane : 1000;
    #pragma unroll
    for (int off = 8; off >= 1; off >>= 1) {
        float om = __shfl_xor(m, off, 16);
        int   oa = __shfl_xor(am, off, 16);
        if (om > m || (om == m && oa < am)) { m = om; am = oa; }
    }
    float s = (lane < 11) ? expf(fin - m) : 0.f;
    #pragma unroll
    for (int off = 8; off >= 1; off >>= 1) s += __shfl_xor(s, off, 16);

    if (lane == 0) {
        scores[b] = m + logf(s);
        int cur = am;
        paths[lbase + 511] = (float)cur;
        for (int t = 511; t >= 1; --t) {
            cur = bp[t][cur];
            paths[lbase + t - 1] = (float)cur;
        }
    }
}

// ---------------------------------------------------------------------------
extern "C" void kernel_launch(void* const* d_in, const int* in_sizes, int n_in,
                              void* d_out, int out_size, void* d_ws, size_t ws_size,
                              hipStream_t stream) {
    const float* emb   = (const float*)d_in[0];
    const int*   imask = (const int*)d_in[1];
    const float* Wihf  = (const float*)d_in[2];
    const float* Whhf  = (const float*)d_in[3];
    const float* bf_   = (const float*)d_in[4];
    const float* Wihb  = (const float*)d_in[5];
    const float* Whhb  = (const float*)d_in[6];
    const float* bb_   = (const float*)d_in[7];
    const float* Wout  = (const float*)d_in[8];
    const float* bout  = (const float*)d_in[9];
    const float* trans = (const float*)d_in[10];

    float* out = (float*)d_out;
    float* ws  = (float*)d_ws;
    float* xw     = ws;                          // 131072*400 f32 = 209.7 MB
    float* hout   = xw + (size_t)131072 * 400;   // 131072*100 f32 = 52.4 MB
    float* logits = hout + (size_t)131072 * 100; // 131072*11  f32 = 5.8 MB

    k_gemm_split<<<5120, 256, 0, stream>>>(emb, Wihf, Wihb, xw);
    k_lstm<<<512, 256, 0, stream>>>(xw, Whhf, Whhb, bf_, bb_, hout);
    k_emis<<<512, 256, 0, stream>>>(hout, Wout, bout, logits);
    k_crf<<<256, 64, 0, stream>>>(logits, imask, trans, out, out + 256);
}

// Round 11
// 1003.519 us; speedup vs baseline: 2.3571x; 1.2189x over previous
//
#include <hip/hip_runtime.h>
#include <math.h>

// Problem constants
// B=256, T=512, E=768, Hd=50, 4*Hd=200, H=100, K=11, START=9, STOP=10, NEG=-1000
// M = B*T = 131072

typedef _Float16 half8 __attribute__((ext_vector_type(8)));
typedef _Float16 half4 __attribute__((ext_vector_type(4)));
typedef float f32x4 __attribute__((ext_vector_type(4)));

// ---------------------------------------------------------------------------
// Kernel 1: xw[M][400] = emb[M][768] @ concat(W_ih_f, W_ih_b)^T
// Split-precision fp16 MFMA (hi+lo, 3 products) => ~fp32 accuracy at f16 rate.
// ---------------------------------------------------------------------------
__global__ __launch_bounds__(256) void k_gemm_split(
    const float* __restrict__ emb,
    const float* __restrict__ Wf,     // [200][768]
    const float* __restrict__ Wb,     // [200][768]
    float* __restrict__ xw)           // [M][400]
{
    __shared__ _Float16 Ah[128 * 64];
    __shared__ _Float16 Al[128 * 64];
    __shared__ _Float16 Bh[80 * 64];
    __shared__ _Float16 Bl[80 * 64];

    const int bid = blockIdx.x;
    const int wg  = (bid & 7) * 640 + (bid >> 3);
    const int mt  = wg / 5;
    const int nb  = wg - mt * 5;
    const size_t m0 = (size_t)mt * 128;
    const int n0 = nb * 80;

    const int tid  = threadIdx.x;
    const int lane = tid & 63;
    const int w    = tid >> 6;        // wave 0..3, rows w*32..+31
    const int grp  = lane >> 4;       // 0..3
    const int r16  = lane & 15;

    f32x4 acc[2][5];
    #pragma unroll
    for (int m = 0; m < 2; ++m)
        #pragma unroll
        for (int n = 0; n < 5; ++n) acc[m][n] = (f32x4){0.f, 0.f, 0.f, 0.f};

    for (int kt = 0; kt < 12; ++kt) {
        const int k0 = kt * 64;
        __syncthreads();

        #pragma unroll
        for (int j = 0; j < 8; ++j) {
            const int flat = j * 256 + tid;      // 0..2047 float4 slots
            const int row  = flat >> 4;          // 0..127
            const int q    = flat & 15;          // float4 col
            const float4 v = *(const float4*)(emb + (m0 + row) * 768 + k0 + q * 4);
            half4 hv, lv;
            hv[0] = (_Float16)v.x; lv[0] = (_Float16)(v.x - (float)hv[0]);
            hv[1] = (_Float16)v.y; lv[1] = (_Float16)(v.y - (float)hv[1]);
            hv[2] = (_Float16)v.z; lv[2] = (_Float16)(v.z - (float)hv[2]);
            hv[3] = (_Float16)v.w; lv[3] = (_Float16)(v.w - (float)hv[3]);
            const int s    = (q >> 1) ^ (row & 7);
            const int addr = row * 64 + s * 8 + (q & 1) * 4;
            *(half4*)(Ah + addr) = hv;
            *(half4*)(Al + addr) = lv;
        }
        #pragma unroll
        for (int j = 0; j < 5; ++j) {
            const int flat = j * 256 + tid;      // 0..1279
            const int row  = flat >> 4;          // 0..79
            const int q    = flat & 15;
            const int n    = n0 + row;
            const float* src = (n < 200) ? (Wf + (size_t)n * 768)
                                         : (Wb + (size_t)(n - 200) * 768);
            const float4 v = *(const float4*)(src + k0 + q * 4);
            half4 hv, lv;
            hv[0] = (_Float16)v.x; lv[0] = (_Float16)(v.x - (float)hv[0]);
            hv[1] = (_Float16)v.y; lv[1] = (_Float16)(v.y - (float)hv[1]);
            hv[2] = (_Float16)v.z; lv[2] = (_Float16)(v.z - (float)hv[2]);
            hv[3] = (_Float16)v.w; lv[3] = (_Float16)(v.w - (float)hv[3]);
            const int s    = (q >> 1) ^ (row & 7);
            const int addr = row * 64 + s * 8 + (q & 1) * 4;
            *(half4*)(Bh + addr) = hv;
            *(half4*)(Bl + addr) = lv;
        }
        __syncthreads();

        #pragma unroll
        for (int ks = 0; ks < 2; ++ks) {
            const int kslot = ks * 4 + grp;
            half8 ah[2], al[2], bh[5], bl[5];
            #pragma unroll
            for (int m = 0; m < 2; ++m) {
                const int row = w * 32 + m * 16 + r16;
                const int ad  = row * 64 + (kslot ^ (row & 7)) * 8;
                ah[m] = *(half8*)(Ah + ad);
                al[m] = *(half8*)(Al + ad);
            }
            #pragma unroll
            for (int n = 0; n < 5; ++n) {
                const int row = n * 16 + r16;
                const int ad  = row * 64 + (kslot ^ (row & 7)) * 8;
                bh[n] = *(half8*)(Bh + ad);
                bl[n] = *(half8*)(Bl + ad);
            }
            #pragma unroll
            for (int m = 0; m < 2; ++m)
                #pragma unroll
                for (int n = 0; n < 5; ++n) {
                    acc[m][n] = __builtin_amdgcn_mfma_f32_16x16x32_f16(ah[m], bh[n], acc[m][n], 0, 0, 0);
                    acc[m][n] = __builtin_amdgcn_mfma_f32_16x16x32_f16(ah[m], bl[n], acc[m][n], 0, 0, 0);
                    acc[m][n] = __builtin_amdgcn_mfma_f32_16x16x32_f16(al[m], bh[n], acc[m][n], 0, 0, 0);
                }
        }
    }

    #pragma unroll
    for (int m = 0; m < 2; ++m) {
        #pragma unroll
        for (int n = 0; n < 5; ++n) {
            #pragma unroll
            for (int i = 0; i < 4; ++i) {
                const size_t row = m0 + w * 32 + m * 16 + (lane >> 4) * 4 + i;
                const int    col = n0 + n * 16 + (lane & 15);
                xw[row * 400 + col] = acc[m][n][i];
            }
        }
    }
}

// ---------------------------------------------------------------------------
// Kernel 2: bidirectional LSTM recurrence. One block per (batch, dir).
// R1 structure verbatim — best measured (457 us) across 7 structural
// variants. The recurrence is bound by per-step weight streaming (~80KB/CU
// from L2 or ~1250cy from LDS) + serial chain; no source-level variant beat
// this. Do not touch without a fundamentally different weight-amortization
// scheme that keeps >=200 blocks.
// ---------------------------------------------------------------------------
__global__ __launch_bounds__(256) void k_lstm(
    const float* __restrict__ xw,     // [131072][400] (fwd gates 0..199, bwd 200..399)
    const float* __restrict__ Whh_f,  // [200][50]
    const float* __restrict__ Whh_b,
    const float* __restrict__ bf_,    // [200]
    const float* __restrict__ bb_,
    float* __restrict__ hout)         // [131072][100] (fwd 0..49, bwd 50..99)
{
    const int b   = blockIdx.x >> 1;
    const int dir = blockIdx.x & 1;
    const int g   = threadIdx.x;

    __shared__ float h_s[52];
    __shared__ float g_s[200];

    const float* Whh  = dir ? Whh_b : Whh_f;
    const float* bias = dir ? bb_ : bf_;

    float w[52];
    float bg = 0.f;
    if (g < 200) {
        #pragma unroll
        for (int j = 0; j < 50; ++j) w[j] = Whh[g * 50 + j];
        w[50] = 0.f; w[51] = 0.f;
        bg = bias[g];
    } else {
        #pragma unroll
        for (int j = 0; j < 52; ++j) w[j] = 0.f;
    }

    if (g < 52) h_s[g] = 0.f;
    float c = 0.f;
    __syncthreads();

    const size_t base = (size_t)b * 512;

    float xv = 0.f;
    {
        int t0 = dir ? 511 : 0;
        if (g < 200) xv = xw[(base + t0) * 400 + dir * 200 + g];
    }

    for (int it = 0; it < 512; ++it) {
        const int t = dir ? (511 - it) : it;
        float xcur = xv;
        if (it + 1 < 512) {
            int tn = dir ? (510 - it) : (it + 1);
            if (g < 200) xv = xw[(base + tn) * 400 + dir * 200 + g];
        }

        float sum = bg + xcur;
        const float4* h4 = (const float4*)h_s;
        #pragma unroll
        for (int q = 0; q < 13; ++q) {
            float4 hv = h4[q];
            sum = fmaf(w[q * 4 + 0], hv.x, sum);
            sum = fmaf(w[q * 4 + 1], hv.y, sum);
            sum = fmaf(w[q * 4 + 2], hv.z, sum);
            sum = fmaf(w[q * 4 + 3], hv.w, sum);
        }
        if (g < 200) g_s[g] = sum;
        __syncthreads();

        if (g < 50) {
            float gi = g_s[g];
            float gf = g_s[g + 50];
            float gg = g_s[g + 100];
            float go = g_s[g + 150];
            float si = 1.f / (1.f + expf(-gi));
            float sf = 1.f / (1.f + expf(-gf));
            float so = 1.f / (1.f + expf(-go));
            c = sf * c + si * tanhf(gg);
            float h = so * tanhf(c);
            hout[(base + t) * 100 + dir * 50 + g] = h;
            h_s[g] = h;
        }
        __syncthreads();
    }
}

// ---------------------------------------------------------------------------
// Kernel 3: emissions logits[bt][11] = hout[bt][100] @ Wout^T + bout
// ---------------------------------------------------------------------------
__global__ __launch_bounds__(256) void k_emis(
    const float* __restrict__ hout,   // [131072][100]
    const float* __restrict__ Wout,   // [11][100]
    const float* __restrict__ bout,   // [11]
    float* __restrict__ logits)       // [131072][11]
{
    __shared__ float Wl[1104];
    __shared__ float bl[11];
    const int tid = threadIdx.x;
    for (int i = tid; i < 1100; i += 256) Wl[i] = Wout[i];
    if (tid < 11) bl[tid] = bout[tid];
    __syncthreads();

    const size_t bt = (size_t)blockIdx.x * 256 + tid;
    const float4* h4 = (const float4*)(hout + bt * 100);
    float acc[11];
    #pragma unroll
    for (int k = 0; k < 11; ++k) acc[k] = bl[k];
    #pragma unroll
    for (int q = 0; q < 25; ++q) {
        float4 v = h4[q];
        #pragma unroll
        for (int k = 0; k < 11; ++k) {
            const float4 wv = *(const float4*)&Wl[k * 100 + q * 4];
            acc[k] = fmaf(v.x, wv.x, fmaf(v.y, wv.y, fmaf(v.z, wv.z, fmaf(v.w, wv.w, acc[k]))));
        }
    }
    #pragma unroll
    for (int k = 0; k < 11; ++k) logits[bt * 11 + k] = acc[k];
}

// ---------------------------------------------------------------------------
// Kernel 4: CRF forward scan + logsumexp score + fused Viterbi backtrace.
// REGISTER-RESIDENT scan: na = f[c] + M + log(sum_p exp(al[p]-M)*E[c][p])
// where E[c][p] = exp(trans[p][c]) is PRECOMPUTED (f[c] is constant over p,
// so it factors out of the softmax and cancels in the p-argmax -> Viterbi
// semantics preserved: first-max, ascending p, over al[p]+tr[p][c]).
// Per step: 11 shfl broadcasts + max tree + 11 HW v_exp + 11 FMA + v_log —
// ZERO LDS round-trips (vs 2 x ~120cy before) and no libm in the loop.
// START column underflows to -inf instead of ~-1000*t; propagates
// identically (exp -> 0, never the argmax). One wave per batch element.
// ---------------------------------------------------------------------------
__global__ __launch_bounds__(64, 1) void k_crf(
    const float* __restrict__ logits,   // [131072][11]
    const int* __restrict__ mask,       // [256][512]
    const float* __restrict__ trans,    // [11][11]
    float* __restrict__ scores,         // [256]
    float* __restrict__ paths)          // [256][512] (as float)
{
    const int b = blockIdx.x;
    const int lane = threadIdx.x;
    const int lanec = (lane < 11) ? lane : 10;   // clamp for safe addressing

    __shared__ unsigned char bp[512][12];

    // per-lane column constants: trc[p] = trans[p][c], E[p] = exp(trc[p])
    float trc[11], E[11];
    #pragma unroll
    for (int p = 0; p < 11; ++p) {
        trc[p] = trans[p * 11 + lanec];
        E[p]   = expf(trc[p]);                   // once; amortized over 512 steps
    }

    float al_c = (lane == 9) ? 0.f : -1000.f;    // alpha[c] lives in lane c (<11)

    const size_t lbase = (size_t)b * 512;

    float f_cur = logits[lbase * 11 + lanec];
    int   m_cur = mask[lbase];

    for (int t = 0; t < 512; ++t) {
        float f_next = 0.f; int m_next = 1;
        if (t + 1 < 512) {
            f_next = logits[(lbase + t + 1) * 11 + lanec];
            m_next = mask[lbase + t + 1];
        }

        // broadcast all 11 alphas to every lane
        float a[11];
        #pragma unroll
        for (int p = 0; p < 11; ++p) a[p] = __shfl(al_c, p);

        // Viterbi: first-max ascending over a[p] + trc[p] (f[c] cancels)
        float vmax = a[0] + trc[0]; int amax = 0;
        #pragma unroll
        for (int p = 1; p < 11; ++p) {
            const float vp = a[p] + trc[p];
            if (vp > vmax) { vmax = vp; amax = p; }
        }

        // common max M over alphas (balanced tree)
        const float m01 = fmaxf(a[0], a[1]),  m23 = fmaxf(a[2], a[3]);
        const float m45 = fmaxf(a[4], a[5]),  m67 = fmaxf(a[6], a[7]);
        const float m89 = fmaxf(a[8], a[9]);
        const float mA  = fmaxf(fmaxf(m01, m23), fmaxf(m45, m67));
        const float M   = fmaxf(mA, fmaxf(m89, a[10]));

        // S = sum_p exp(a[p]-M) * E[p]  (HW exp; balanced add tree)
        float e[11];
        #pragma unroll
        for (int p = 0; p < 11; ++p) e[p] = __expf(a[p] - M) * E[p];
        const float s01 = e[0] + e[1], s23 = e[2] + e[3];
        const float s45 = e[4] + e[5], s67 = e[6] + e[7];
        const float s89 = e[8] + e[9];
        const float S = ((s01 + s23) + (s45 + s67)) + (s89 + e[10]);

        const float na = f_cur + (M + __logf(S));

        if (lane < 11) {
            if (m_cur > 0) {
                al_c = na;
                bp[t][lane] = (unsigned char)amax;
            } else {
                bp[t][lane] = (unsigned char)lane;
            }
        }
        f_cur = f_next;
        m_cur = m_next;
    }

    // final scores + argmax (STOP = 10) — unchanged from the passing version
    float fin = (lane < 11) ? (al_c + trans[lane * 11 + 10]) : -1e30f;
    float m = fin;
    int am = (lane < 11) ? lane : 1000;
    #pragma unroll
    for (int off = 8; off >= 1; off >>= 1) {
        float om = __shfl_xor(m, off, 16);
        int   oa = __shfl_xor(am, off, 16);
        if (om > m || (om == m && oa < am)) { m = om; am = oa; }
    }
    float s = (lane < 11) ? expf(fin - m) : 0.f;
    #pragma unroll
    for (int off = 8; off >= 1; off >>= 1) s += __shfl_xor(s, off, 16);

    if (lane == 0) {
        scores[b] = m + logf(s);
        int cur = am;
        paths[lbase + 511] = (float)cur;
        for (int t = 511; t >= 1; --t) {
            cur = bp[t][cur];
            paths[lbase + t - 1] = (float)cur;
        }
    }
}

// ---------------------------------------------------------------------------
extern "C" void kernel_launch(void* const* d_in, const int* in_sizes, int n_in,
                              void* d_out, int out_size, void* d_ws, size_t ws_size,
                              hipStream_t stream) {
    const float* emb   = (const float*)d_in[0];
    const int*   imask = (const int*)d_in[1];
    const float* Wihf  = (const float*)d_in[2];
    const float* Whhf  = (const float*)d_in[3];
    const float* bf_   = (const float*)d_in[4];
    const float* Wihb  = (const float*)d_in[5];
    const float* Whhb  = (const float*)d_in[6];
    const float* bb_   = (const float*)d_in[7];
    const float* Wout  = (const float*)d_in[8];
    const float* bout  = (const float*)d_in[9];
    const float* trans = (const float*)d_in[10];

    float* out = (float*)d_out;
    float* ws  = (float*)d_ws;
    float* xw     = ws;                          // 131072*400 f32 = 209.7 MB
    float* hout   = xw + (size_t)131072 * 400;   // 131072*100 f32 = 52.4 MB
    float* logits = hout + (size_t)131072 * 100; // 131072*11  f32 = 5.8 MB

    k_gemm_split<<<5120, 256, 0, stream>>>(emb, Wihf, Wihb, xw);
    k_lstm<<<512, 256, 0, stream>>>(xw, Whhf, Whhb, bf_, bb_, hout);
    k_emis<<<512, 256, 0, stream>>>(hout, Wout, bout, logits);
    k_crf<<<256, 64, 0, stream>>>(logits, imask, trans, out, out + 256);
}